// Round 10
// baseline (498.668 us; speedup 1.0000x reference)
//
#include <hip/hip_runtime.h>
#include <hip/hip_cooperative_groups.h>
#include <hip/hip_bf16.h>
#include <cstdint>

namespace cg = cooperative_groups;

#define NNODES 20000
#define NEDGES 640000
#define ETOT   (NEDGES + NNODES)
#define NGROUP 64
#define HC     256
#define DOUT   32
#define TPB    256
#define NTILE  (NNODES / 32)         // 625 (exact)
#define NSCANW ((NNODES + 63) / 64)  // 313
#define SCAT_BLOCKS ((ETOT + 255) / 256)

typedef short bf16x8 __attribute__((ext_vector_type(8)));
typedef short s16x4  __attribute__((ext_vector_type(4)));
typedef float f32x4  __attribute__((ext_vector_type(4)));
typedef float f32x2  __attribute__((ext_vector_type(2)));

__device__ __forceinline__ float b2f(__hip_bfloat16 v) { return __bfloat162float(v); }
__device__ __forceinline__ float bs2f(short v) {
    union { unsigned int u; float f; } c; c.u = ((unsigned int)(unsigned short)v) << 16; return c.f;
}
__device__ __forceinline__ short f2bs(float v) {
    __hip_bfloat16 b = __float2bfloat16(v);
    union { __hip_bfloat16 b; short s; } u; u.b = b; return u.s;
}
__device__ __forceinline__ float ldf(const void* __restrict__ p, size_t i, int bf) {
    return bf ? __bfloat162float(((const __hip_bfloat16*)p)[i]) : ((const float*)p)[i];
}
__device__ __forceinline__ int ld_idx(const int* __restrict__ p, size_t i, int f64) {
    return f64 ? p[2 * i] : p[i];
}
__device__ __forceinline__ int probe_i64(const int* __restrict__ ei) {
    int l = threadIdx.x & 63;
    unsigned long long b = __ballot(ei[2 * l + 1] == 0);
    return (__popcll(b) > 48) ? 1 : 0;
}
__device__ __forceinline__ int probe_bf(const unsigned int* __restrict__ xw) {
    int l = threadIdx.x & 63;
    unsigned long long b = __ballot((xw[l] >> 14) & 1);
    return (__popcll(b) < 16) ? 1 : 0;
}

// ---- GEMM stage: 32-row tiles, 4 waves: (row-half rh, col-half ch). acc[8]. Grid-stride. ----
// A frag: lane holds A[m=lane&15][k=(lane>>4)*8+j]; B mirrors with n=lane&15.
// D frag: col=lane&15, row=(lane>>4)*4+reg (m89/m91-verified).
__device__ void gemm_stage(const void* __restrict__ A, const __hip_bfloat16* __restrict__ Bt,
                           __hip_bfloat16* __restrict__ H,
                           const void* __restrict__ a_src, const void* __restrict__ a_dst,
                           float* __restrict__ es4, float* __restrict__ ed4,
                           int bf, int abf) {
    int tid = threadIdx.x;
    int w = tid >> 6, lane = tid & 63, mr = lane & 15, quad = lane >> 4;
    int ch = w >> 1, rh = w & 1;
    for (int tile = blockIdx.x; tile < NTILE; tile += gridDim.x) {
        int r0 = tile * 32 + rh * 16;
        f32x4 acc[8];
#pragma unroll
        for (int j = 0; j < 8; j++) acc[j] = (f32x4){0.f, 0.f, 0.f, 0.f};
        size_t rowoff = (size_t)(r0 + mr) * HC;
        for (int kk = 0; kk < HC; kk += 32) {
            bf16x8 a;
            if (abf) {
                a = *reinterpret_cast<const bf16x8*>((const __hip_bfloat16*)A + rowoff + kk + quad * 8);
            } else {
                const float* af = (const float*)A + rowoff + kk + quad * 8;
                f32x4 lo = *reinterpret_cast<const f32x4*>(af);
                f32x4 hi = *reinterpret_cast<const f32x4*>(af + 4);
#pragma unroll
                for (int ii = 0; ii < 4; ii++) { a[ii] = f2bs(lo[ii]); a[ii + 4] = f2bs(hi[ii]); }
            }
#pragma unroll
            for (int j = 0; j < 8; j++) {
                bf16x8 b = *reinterpret_cast<const bf16x8*>(
                    Bt + (size_t)(ch * 128 + j * 16 + mr) * HC + kk + quad * 8);
                acc[j] = __builtin_amdgcn_mfma_f32_16x16x32_bf16(a, b, acc[j], 0, 0, 0);
            }
        }
#pragma unroll
        for (int j = 0; j < 8; j++)
#pragma unroll
            for (int r = 0; r < 4; r++)
                H[(size_t)(r0 + quad * 4 + r) * HC + ch * 128 + j * 16 + mr] = __float2bfloat16(acc[j][r]);
        float ps[2][4], pd[2][4];
#pragma unroll
        for (int h = 0; h < 2; h++)
#pragma unroll
            for (int r = 0; r < 4; r++) { ps[h][r] = 0.f; pd[h][r] = 0.f; }
#pragma unroll
        for (int j = 0; j < 8; j++) {
            int h = j >> 2;
            size_t col = (size_t)ch * 128 + j * 16 + mr;
            float asv = ldf(a_src, col, bf);
            float adv = ldf(a_dst, col, bf);
#pragma unroll
            for (int r = 0; r < 4; r++) {
                ps[h][r] = fmaf(acc[j][r], asv, ps[h][r]);
                pd[h][r] = fmaf(acc[j][r], adv, pd[h][r]);
            }
        }
#pragma unroll
        for (int o = 1; o < 16; o <<= 1)
#pragma unroll
            for (int h = 0; h < 2; h++)
#pragma unroll
                for (int r = 0; r < 4; r++) {
                    ps[h][r] += __shfl_xor(ps[h][r], o);
                    pd[h][r] += __shfl_xor(pd[h][r], o);
                }
        if (mr == 0)
#pragma unroll
            for (int r = 0; r < 4; r++) {
                int row = r0 + quad * 4 + r;
                *reinterpret_cast<f32x2*>(es4 + (size_t)row * 4 + ch * 2) = (f32x2){ps[0][r], ps[1][r]};
                *reinterpret_cast<f32x2*>(ed4 + (size_t)row * 4 + ch * 2) = (f32x2){pd[0][r], pd[1][r]};
            }
    }
}

// ---- agg stage: wave per node, online softmax, 8-way unrolled gather. Grid-stride.
// outx!=nullptr: store relu'd bf16 row. else: atomicAdd relu'd row into sx[batch[n]].
__device__ void agg_stage(const __hip_bfloat16* __restrict__ Hb,
                          const float* __restrict__ es4, const float* __restrict__ ed4,
                          const void* __restrict__ bias,
                          const int* __restrict__ off, const int* __restrict__ csr,
                          __hip_bfloat16* __restrict__ outx,
                          float* __restrict__ sx, const int* __restrict__ bat, int f64,
                          int bf, float (*p_lds)[256], int (*s_lds)[64]) {
    int tid = threadIdx.x;
    int wv = tid >> 6, l = tid & 63, hd = l >> 4;
    int gwave  = blockIdx.x * 4 + wv;
    int stride = gridDim.x * 4;
    for (int n = gwave; n < NNODES; n += stride) {
        int base = off[n], deg = off[n + 1] - base;
        f32x4 edv = *reinterpret_cast<const f32x4*>(ed4 + (size_t)n * 4);
        f32x4 m    = (f32x4){-INFINITY, -INFINITY, -INFINITY, -INFINITY};
        f32x4 dsum = (f32x4){0.f, 0.f, 0.f, 0.f};
        f32x4 acc  = (f32x4){0.f, 0.f, 0.f, 0.f};
        for (int c0 = 0; c0 < deg; c0 += 64) {
            int cn = min(deg - c0, 64);
            f32x4 ev;
            if (l < cn) {
                int s = csr[base + c0 + l];
                s_lds[wv][l] = s;
                f32x4 e = *reinterpret_cast<const f32x4*>(es4 + (size_t)s * 4);
#pragma unroll
                for (int h = 0; h < 4; h++) {
                    float t = e[h] + edv[h];
                    ev[h] = (t > 0.f) ? t : 0.2f * t;
                }
            } else {
#pragma unroll
                for (int h = 0; h < 4; h++) ev[h] = -INFINITY;
            }
            f32x4 mc = ev;
#pragma unroll
            for (int o = 32; o; o >>= 1)
#pragma unroll
                for (int h = 0; h < 4; h++) mc[h] = fmaxf(mc[h], __shfl_xor(mc[h], o));
            f32x4 al, pv;
#pragma unroll
            for (int h = 0; h < 4; h++) {
                float nm = fmaxf(m[h], mc[h]);
                al[h] = __expf(m[h] - nm);
                m[h]  = nm;
            }
#pragma unroll
            for (int h = 0; h < 4; h++) pv[h] = (l < cn) ? __expf(ev[h] - m[h]) : 0.f;
            f32x4 sc = pv;
#pragma unroll
            for (int o = 32; o; o >>= 1)
#pragma unroll
                for (int h = 0; h < 4; h++) sc[h] += __shfl_xor(sc[h], o);
#pragma unroll
            for (int h = 0; h < 4; h++) dsum[h] = dsum[h] * al[h] + sc[h];
            acc *= al[hd];
            *reinterpret_cast<f32x4*>(&p_lds[wv][l * 4]) = pv;
            int jm = cn & ~7;
            for (int j = 0; j < jm; j += 8) {
                s16x4 hv[8];
                float pj[8];
#pragma unroll
                for (int i = 0; i < 8; i++) {
                    int sj = s_lds[wv][j + i];
                    hv[i] = *reinterpret_cast<const s16x4*>(Hb + (size_t)sj * HC + l * 4);
                    pj[i] = p_lds[wv][(j + i) * 4 + hd];
                }
#pragma unroll
                for (int i = 0; i < 8; i++)
#pragma unroll
                    for (int k = 0; k < 4; k++) acc[k] = fmaf(pj[i], bs2f(hv[i][k]), acc[k]);
            }
            for (int j = jm; j < cn; j++) {
                int sj  = s_lds[wv][j];
                float p = p_lds[wv][j * 4 + hd];
                s16x4 hv = *reinterpret_cast<const s16x4*>(Hb + (size_t)sj * HC + l * 4);
#pragma unroll
                for (int k = 0; k < 4; k++) acc[k] = fmaf(p, bs2f(hv[k]), acc[k]);
            }
        }
        float dd = fmaxf(dsum[hd], 1e-16f);
        if (outx) {
            s16x4 ov;
#pragma unroll
            for (int k = 0; k < 4; k++) {
                float v = acc[k] / dd + ldf(bias, (size_t)l * 4 + k, bf);
                ov[k] = f2bs(fmaxf(v, 0.f));
            }
            *reinterpret_cast<s16x4*>(outx + (size_t)n * HC + l * 4) = ov;
        } else {
            int g = ld_idx(bat, n, f64);
#pragma unroll
            for (int k = 0; k < 4; k++) {
                float v = fmaxf(acc[k] / dd + ldf(bias, (size_t)l * 4 + k, bf), 0.f);
                atomicAdd(&sx[(size_t)g * HC + l * 4 + k], v);
            }
        }
    }
}

__device__ void final_stage(const float* __restrict__ sx, const void* __restrict__ Wp,
                            const void* __restrict__ bp, const int* __restrict__ bat,
                            int f64, int bf, int gtid, void* __restrict__ out) {
    int g = gtid >> 5, c = gtid & 31;
    int lo = 0, hi = NNODES;
    while (lo < hi) { int mm = (lo + hi) >> 1; if (ld_idx(bat, mm, f64) < g) lo = mm + 1; else hi = mm; }
    int start = lo;
    hi = NNODES;
    while (lo < hi) { int mm = (lo + hi) >> 1; if (ld_idx(bat, mm, f64) < g + 1) lo = mm + 1; else hi = mm; }
    int ct = lo - start;
    float acc = 0.f;
    const float* sxg = sx + (size_t)g * HC;
    for (int k = 0; k < HC; k++) acc = fmaf(sxg[k], ldf(Wp, (size_t)k * DOUT + c, bf), acc);
    float v = (ct > 0) ? (acc / ct + ldf(bp, c, bf)) : 0.f;
    if (bf) ((__hip_bfloat16*)out)[gtid] = __float2bfloat16(v);
    else    ((float*)out)[gtid] = v;
}

// ================= cooperative mega kernel =================
__global__ __launch_bounds__(TPB) void k_mega(
    const void* __restrict__ x, const int* __restrict__ ei, const int* __restrict__ bat,
    const void* __restrict__ W1, const void* __restrict__ as1, const void* __restrict__ ad1,
    const void* __restrict__ b1,
    const void* __restrict__ W2, const void* __restrict__ as2, const void* __restrict__ ad2,
    const void* __restrict__ b2,
    const void* __restrict__ Wp, const void* __restrict__ bp, void* __restrict__ out,
    __hip_bfloat16* __restrict__ hb, __hip_bfloat16* __restrict__ xb,
    __hip_bfloat16* __restrict__ Wt1, __hip_bfloat16* __restrict__ Wt2,
    float* __restrict__ es, float* __restrict__ ed,
    int* __restrict__ deg, int* __restrict__ cur, int* __restrict__ off, int* __restrict__ csr,
    float* __restrict__ sx, int* __restrict__ presum, int* __restrict__ wsum,
    int* __restrict__ wexc) {
    cg::grid_group grid = cg::this_grid();
    __shared__ float p_lds[4][256];
    __shared__ int   s_lds[4][64];
    int tid  = threadIdx.x;
    int gtid = blockIdx.x * TPB + tid;
    int nthr = gridDim.x * TPB;
    int lane = tid & 63;
    int wv   = tid >> 6;
    int gwave = gtid >> 6;
    int f64 = probe_i64(ei);
    int bf  = probe_bf((const unsigned int*)x);

    // S0: zero deg + sx
    for (int i = gtid; i < NNODES; i += nthr) deg[i] = 0;
    for (int i = gtid; i < NGROUP * HC; i += nthr) sx[i] = 0.f;
    grid.sync();

    // S1: histogram + weight transposes
    for (int i = gtid; i < ETOT; i += nthr) {
        int d = (i < NEDGES) ? ld_idx(ei, (size_t)NEDGES + i, f64) : (i - NEDGES);
        atomicAdd(&deg[d], 1);
    }
    for (int i = gtid; i < 2 * 65536; i += nthr) {
        int which = i >> 16;
        int j = i & 65535;
        int k = j >> 8, n = j & 255;
        const void* W = which ? W2 : W1;
        __hip_bfloat16* Wt = which ? Wt2 : Wt1;
        Wt[(size_t)n * 256 + k] = __float2bfloat16(ldf(W, (size_t)k * 256 + n, bf));
    }
    grid.sync();

    // S2a: per-wave inclusive scan of deg (needs nthr >= NNODES; host enforces grid >= 128)
    {
        int v = (gtid < NNODES) ? deg[gtid] : 0;
        int s = v;
#pragma unroll
        for (int o = 1; o < 64; o <<= 1) { int u = __shfl_up(s, o); if (lane >= o) s += u; }
        if (gtid < NNODES) presum[gtid] = s;
        if (lane == 63 && gwave < NSCANW) wsum[gwave] = s;
    }
    grid.sync();
    // S2b: one wave scans the NSCANW wave totals (exclusive)
    if (blockIdx.x == 0 && wv == 0) {
        int carry = 0;
        for (int c0 = 0; c0 < NSCANW; c0 += 64) {
            int idx = c0 + lane;
            int v = (idx < NSCANW) ? wsum[idx] : 0;
            int s = v;
#pragma unroll
            for (int o = 1; o < 64; o <<= 1) { int u = __shfl_up(s, o); if (lane >= o) s += u; }
            if (idx < NSCANW) wexc[idx] = carry + s - v;
            carry += __shfl(s, 63);
        }
    }
    grid.sync();
    // S2c: off/cur
    if (gtid < NNODES) {
        int d = deg[gtid];
        int o_ = wexc[gwave] + presum[gtid] - d;
        off[gtid] = o_;
        cur[gtid] = o_;
    }
    if (gtid == 0) off[NNODES] = ETOT;
    grid.sync();

    // S3: scatter
    for (int i = gtid; i < ETOT; i += nthr) {
        int s, d;
        if (i < NEDGES) { s = ld_idx(ei, i, f64); d = ld_idx(ei, (size_t)NEDGES + i, f64); }
        else            { s = d = i - NEDGES; }
        int pos = atomicAdd(&cur[d], 1);
        csr[pos] = s;
    }
    grid.sync();

    // S4..S7
    gemm_stage(x, Wt1, hb, as1, ad1, es, ed, bf, bf);
    grid.sync();
    agg_stage(hb, es, ed, b1, off, csr, xb, nullptr, nullptr, f64, bf, p_lds, s_lds);
    grid.sync();
    gemm_stage(xb, Wt2, hb, as2, ad2, es, ed, bf, 1);
    grid.sync();
    agg_stage(hb, es, ed, b2, off, csr, nullptr, sx, bat, f64, bf, p_lds, s_lds);
    grid.sync();

    // S8: final projection + mean
    if (gtid < NGROUP * DOUT) final_stage(sx, Wp, bp, bat, f64, bf, gtid, out);
}

// ================= fallback standalone kernels (round-8 proven path) =================
__global__ void k_hist(const int* __restrict__ ei, int* __restrict__ deg) {
    int f = probe_i64(ei);
    int i = blockIdx.x * blockDim.x + threadIdx.x;
    if (i >= ETOT) return;
    int d = (i < NEDGES) ? ld_idx(ei, (size_t)NEDGES + i, f) : (i - NEDGES);
    atomicAdd(&deg[d], 1);
}

__global__ void k_scan(const int* __restrict__ deg, int* __restrict__ off, int* __restrict__ cur) {
    __shared__ unsigned short dl[NNODES];
    __shared__ int wtot[8];
    int t = threadIdx.x;
    for (int i = t; i < NNODES; i += 512) dl[i] = (unsigned short)deg[i];
    __syncthreads();
    const int chunk = (NNODES + 511) / 512;
    int s = t * chunk, e = min(s + chunk, NNODES);
    int sum = 0;
    for (int i = s; i < e; i++) sum += dl[i];
    int lane = t & 63, wv = t >> 6;
    int v = sum;
#pragma unroll
    for (int o = 1; o < 64; o <<= 1) { int u = __shfl_up(v, o); if (lane >= o) v += u; }
    if (lane == 63) wtot[wv] = v;
    __syncthreads();
    int woff = 0;
    for (int i = 0; i < wv; i++) woff += wtot[i];
    int run = woff + v - sum;
    for (int i = s; i < e; i++) { off[i] = run; cur[i] = run; run += dl[i]; }
    if (t == 511) off[NNODES] = ETOT;
}

__global__ void k_scatter_wt(const int* __restrict__ ei, int* __restrict__ cur,
                             int* __restrict__ csr,
                             const void* __restrict__ W1, const void* __restrict__ W2,
                             __hip_bfloat16* __restrict__ Wt1, __hip_bfloat16* __restrict__ Wt2) {
    int b = blockIdx.x;
    if (b < SCAT_BLOCKS) {
        int f = probe_i64(ei);
        int i = b * 256 + threadIdx.x;
        if (i >= ETOT) return;
        int s, d;
        if (i < NEDGES) { s = ld_idx(ei, i, f); d = ld_idx(ei, (size_t)NEDGES + i, f); }
        else            { s = d = i - NEDGES; }
        int pos = atomicAdd(&cur[d], 1);
        csr[pos] = s;
    } else {
        int bf = probe_bf((const unsigned int*)W1);
        int i = (b - SCAT_BLOCKS) * 256 + threadIdx.x;
        int which = i >> 16;
        int j = i & 65535;
        int k = j >> 8, n = j & 255;
        const void* W = which ? W2 : W1;
        __hip_bfloat16* Wt = which ? Wt2 : Wt1;
        Wt[(size_t)n * 256 + k] = __float2bfloat16(ldf(W, (size_t)k * 256 + n, bf));
    }
}

__global__ __launch_bounds__(TPB) void k_gemm(const void* __restrict__ A,
                                              const __hip_bfloat16* __restrict__ Bt,
                                              __hip_bfloat16* __restrict__ H,
                                              const void* __restrict__ a_src,
                                              const void* __restrict__ a_dst,
                                              float* __restrict__ es4, float* __restrict__ ed4,
                                              const void* __restrict__ xprobe, int force_bf) {
    int bf = probe_bf((const unsigned int*)xprobe);
    gemm_stage(A, Bt, H, a_src, a_dst, es4, ed4, bf, force_bf | bf);
}

__global__ __launch_bounds__(TPB) void k_agg(const __hip_bfloat16* __restrict__ Hb,
                                             const float* __restrict__ es4, const float* __restrict__ ed4,
                                             const void* __restrict__ bias,
                                             const int* __restrict__ off, const int* __restrict__ csr,
                                             const void* __restrict__ xprobe, const int* __restrict__ ei,
                                             __hip_bfloat16* __restrict__ outx,
                                             float* __restrict__ sx, const int* __restrict__ bat) {
    __shared__ float p_lds[4][256];
    __shared__ int   s_lds[4][64];
    int bf  = probe_bf((const unsigned int*)xprobe);
    int f64 = probe_i64(ei);
    agg_stage(Hb, es4, ed4, bias, off, csr, outx, sx, bat, f64, bf, p_lds, s_lds);
}

__global__ __launch_bounds__(TPB) void k_final(const float* __restrict__ sx,
                                               const void* __restrict__ Wp,
                                               const void* __restrict__ bp,
                                               const int* __restrict__ bat,
                                               const int* __restrict__ ei,
                                               const void* __restrict__ xprobe,
                                               void* __restrict__ out) {
    int f64 = probe_i64(ei);
    int bf  = probe_bf((const unsigned int*)xprobe);
    int gtid = blockIdx.x * TPB + threadIdx.x;
    if (gtid < NGROUP * DOUT) final_stage(sx, Wp, bp, bat, f64, bf, gtid, out);
}

extern "C" void kernel_launch(void* const* d_in, const int* in_sizes, int n_in,
                              void* d_out, int out_size, void* d_ws, size_t ws_size,
                              hipStream_t stream) {
    (void)in_sizes; (void)n_in; (void)out_size; (void)ws_size;
    const void* x   = d_in[0];
    const int*  ei  = (const int*)d_in[1];
    const int*  bat = (const int*)d_in[2];
    const void* W1  = d_in[3];
    const void* as1 = d_in[4];
    const void* ad1 = d_in[5];
    const void* b1  = d_in[6];
    const void* W2  = d_in[7];
    const void* as2 = d_in[8];
    const void* ad2 = d_in[9];
    const void* b2  = d_in[10];
    const void* Wp  = d_in[11];
    const void* bp  = d_in[12];
    void* out = d_out;

    char* ws = (char*)d_ws;
    size_t o = 0;
    auto alloc = [&](size_t bytes) -> char* {
        char* p = ws + o;
        o += (bytes + 255) & ~(size_t)255;
        return p;
    };
    __hip_bfloat16* hb  = (__hip_bfloat16*)alloc((size_t)NNODES * HC * 2);
    __hip_bfloat16* xb  = (__hip_bfloat16*)alloc((size_t)NNODES * HC * 2);
    __hip_bfloat16* Wt1 = (__hip_bfloat16*)alloc((size_t)HC * HC * 2);
    __hip_bfloat16* Wt2 = (__hip_bfloat16*)alloc((size_t)HC * HC * 2);
    float* es = (float*)alloc((size_t)NNODES * 4 * 4);
    float* ed = (float*)alloc((size_t)NNODES * 4 * 4);
    // deg + sx adjacent for single memset in fallback
    char* zbase = alloc(((size_t)NNODES * 4 + 255 & ~(size_t)255) + (size_t)NGROUP * HC * 4);
    int*   deg = (int*)zbase;
    float* sx  = (float*)(zbase + ((size_t)NNODES * 4 + 255 & ~(size_t)255));
    size_t zlen = ((size_t)NNODES * 4 + 255 & ~(size_t)255) + (size_t)NGROUP * HC * 4;
    int* cur  = (int*)alloc((size_t)NNODES * 4);
    int* off  = (int*)alloc((size_t)(NNODES + 1) * 4);
    int* csr  = (int*)alloc((size_t)ETOT * 4);
    int* presum = (int*)alloc((size_t)NNODES * 4);
    int* wsum   = (int*)alloc((size_t)NSCANW * 4);
    int* wexc   = (int*)alloc((size_t)NSCANW * 4);

    // ---- try cooperative mega kernel, grid sized from the occupancy API ----
    int nb = 0;
    hipError_t rc = hipOccupancyMaxActiveBlocksPerMultiprocessor(
        &nb, (const void*)k_mega, TPB, 0);
    bool mega_done = false;
    if (rc == hipSuccess && nb > 0) {
        int grid = nb * 256;           // 256 CUs on MI355X
        if (grid > 1024) grid = 1024;
        if (grid >= 128) {             // need >= 79 blocks for the scan stage
            void* kargs[] = {
                (void*)&x, (void*)&ei, (void*)&bat,
                (void*)&W1, (void*)&as1, (void*)&ad1, (void*)&b1,
                (void*)&W2, (void*)&as2, (void*)&ad2, (void*)&b2,
                (void*)&Wp, (void*)&bp, (void*)&out,
                (void*)&hb, (void*)&xb, (void*)&Wt1, (void*)&Wt2,
                (void*)&es, (void*)&ed, (void*)&deg, (void*)&cur, (void*)&off, (void*)&csr,
                (void*)&sx, (void*)&presum, (void*)&wsum, (void*)&wexc,
            };
            rc = hipLaunchCooperativeKernel((const void*)k_mega, dim3(grid), dim3(TPB),
                                            kargs, 0, stream);
            mega_done = (rc == hipSuccess);
        }
    }

    if (!mega_done) {
        // ---- fallback: proven multi-dispatch path ----
        hipMemsetAsync(zbase, 0, zlen, stream);
        k_hist<<<(ETOT + 255) / 256, 256, 0, stream>>>(ei, deg);
        k_scan<<<1, 512, 0, stream>>>(deg, off, cur);
        k_scatter_wt<<<SCAT_BLOCKS + 512, 256, 0, stream>>>(ei, cur, csr, W1, W2, Wt1, Wt2);
        k_gemm<<<NTILE, TPB, 0, stream>>>(x, Wt1, hb, as1, ad1, es, ed, x, 0);
        k_agg<<<NNODES / 4, TPB, 0, stream>>>(hb, es, ed, b1, off, csr, x, ei, xb, nullptr, nullptr);
        k_gemm<<<NTILE, TPB, 0, stream>>>(xb, Wt2, hb, as2, ad2, es, ed, x, 1);
        k_agg<<<NNODES / 4, TPB, 0, stream>>>(hb, es, ed, b2, off, csr, x, ei, nullptr, sx, bat);
        k_final<<<8, TPB, 0, stream>>>(sx, Wp, bp, bat, ei, x, out);
    }
}